// Round 1
// baseline (331.854 us; speedup 1.0000x reference)
//
#include <hip/hip_runtime.h>

// ConvLSTM cell on MI355X (gfx950).
// B=32, C_IN=32, HC=64, H=W=64, K=3. Implicit GEMM: M=256 (4 gates x 64 oc),
// K=864 (96 ch x 9 taps), N=131072 positions, bf16 MFMA 16x16x32, fp32 accum.

#define B_   32
#define CIN  32
#define HC_  64
#define HH   64
#define WW   64

#define A_ELEMS (16 * 27 * 64 * 8)   // 221184 bf16 elements of packed A

typedef __attribute__((ext_vector_type(8))) short short8;
typedef __attribute__((ext_vector_type(4))) float floatx4;

struct PackArgs {
    const float* wx[4]; const float* wh[4];
    const float* bx[4]; const float* bh[4];
};

__device__ __forceinline__ short f2bf(float f) {
    unsigned u = __float_as_uint(f);
    u += 0x7FFFu + ((u >> 16) & 1u);   // round-to-nearest-even
    return (short)(u >> 16);
}

// Pack weights into MFMA A-fragment order:
// flat idx = ((s*27 + kc)*64 + lane)*8 + j
//   s = 16-row M-subtile (m = 16*s + (lane&15)), gate = m>>6, oc = m&63
//   kc = (ky*3 + kx)*3 + sub ; k-in-chunk = (lane>>4)*8 + j ; c = sub*32 + kik
__global__ __launch_bounds__(256) void pack_weights(PackArgs pa, short* a_pk, float* bias) {
    int idx = blockIdx.x * 256 + threadIdx.x;
    if (idx < A_ELEMS) {
        int j    = idx & 7;
        int lane = (idx >> 3) & 63;
        int rest = idx >> 9;
        int kc   = rest % 27;
        int s    = rest / 27;
        int quad = lane >> 4, lo = lane & 15;
        int m = s * 16 + lo, gate = m >> 6, oc = m & 63;
        int tap = kc / 3, sub = kc - 3 * tap;
        int ky = tap / 3, kx = tap - 3 * ky;
        int c = sub * 32 + quad * 8 + j;
        float v = (c < CIN)
            ? pa.wx[gate][((oc * CIN + c) * 3 + ky) * 3 + kx]
            : pa.wh[gate][((oc * HC_ + (c - CIN)) * 3 + ky) * 3 + kx];
        a_pk[idx] = f2bf(v);
    }
    if (idx < 256) {
        int gate = idx >> 6, oc = idx & 63;
        bias[idx] = pa.bx[gate][oc] + pa.bh[gate][oc];
    }
}

// One block: batch b, output rows y0..y0+1, all 64 cols, all 256 gate-channels.
// 8 waves: wave = (nh<<2)|ocp ; wave computes oc in [16*ocp,16*ocp+16) for all
// 4 gates (M-subtiles s = ms*4+ocp, ms = gate) at row y0+nh.
__global__ __launch_bounds__(512) void convlstm_main(
    const float* __restrict__ xin, const float* __restrict__ hin,
    const float* __restrict__ cin, const short* __restrict__ a_pk,
    const float* __restrict__ bias, float* __restrict__ out)
{
    // [4 halo rows][66 cols][96 ch padded to 104] bf16 = 54912 B
    __shared__ __align__(16) short in_s[4 * 66 * 104];

    const int tid = threadIdx.x;
    const int b  = blockIdx.x >> 5;
    const int y0 = (blockIdx.x & 31) * 2;

    // ---- stage x (ch 0..31) + h (ch 32..95), rows y0-1..y0+2, with zero pad
    {
        const int col = tid & 63;
        const int pr  = tid >> 6;
        for (int p = pr; p < 384; p += 8) {          // 384 = 4 rows * 96 ch
            const int row = p / 96;
            const int c   = p - row * 96;
            const int yy  = y0 - 1 + row;
            float v = 0.f;
            if (yy >= 0 && yy < HH)
                v = (c < CIN) ? xin[((b * CIN + c) * HH + yy) * WW + col]
                              : hin[((b * HC_ + (c - CIN)) * HH + yy) * WW + col];
            in_s[(row * 66 + col + 1) * 104 + c] = f2bf(v);
            if (col == 0)  in_s[(row * 66 + 0 ) * 104 + c] = 0;
            if (col == 63) in_s[(row * 66 + 65) * 104 + c] = 0;
        }
    }
    __syncthreads();

    const int wv = tid >> 6, lane = tid & 63;
    const int lo = lane & 15, quad = lane >> 4;
    const int ocp = wv & 3, nh = wv >> 2;

    floatx4 acc[4][4];
    #pragma unroll
    for (int ms = 0; ms < 4; ++ms)
        #pragma unroll
        for (int ns = 0; ns < 4; ++ns)
            acc[ms][ns] = (floatx4){0.f, 0.f, 0.f, 0.f};

    const short8* Ap = (const short8*)a_pk;

    for (int ky = 0; ky < 3; ++ky)
    for (int kx = 0; kx < 3; ++kx) {
        #pragma unroll
        for (int sub = 0; sub < 3; ++sub) {
            const int kc = (ky * 3 + kx) * 3 + sub;
            short8 af[4];
            #pragma unroll
            for (int ms = 0; ms < 4; ++ms)
                af[ms] = Ap[((ms * 4 + ocp) * 27 + kc) * 64 + lane];
            const int base = ((nh + ky) * 66 + kx + lo) * 104 + sub * 32 + quad * 8;
            short8 bfr[4];
            #pragma unroll
            for (int ns = 0; ns < 4; ++ns)
                bfr[ns] = *(const short8*)&in_s[base + ns * 16 * 104];
            #pragma unroll
            for (int ms = 0; ms < 4; ++ms)
                #pragma unroll
                for (int ns = 0; ns < 4; ++ns)
                    acc[ms][ns] = __builtin_amdgcn_mfma_f32_16x16x32_bf16(
                        af[ms], bfr[ns], acc[ms][ns], 0, 0, 0);
        }
    }

    // ---- LSTM elementwise epilogue (this wave owns all 4 gates for its ocs)
    const int y = y0 + nh;
    const size_t plane = (size_t)B_ * HC_ * HH * WW;   // offset of c_new output
    #pragma unroll
    for (int ns = 0; ns < 4; ++ns) {
        const int x = ns * 16 + lo;
        #pragma unroll
        for (int r = 0; r < 4; ++r) {
            const int oc = ocp * 16 + quad * 4 + r;
            float zi = acc[0][ns][r] + bias[oc];
            float zf = acc[1][ns][r] + bias[64 + oc];
            float zo = acc[2][ns][r] + bias[128 + oc];
            float zg = acc[3][ns][r] + bias[192 + oc];
            float ig = 1.f / (1.f + __expf(-zi));
            float fg = 1.f / (1.f + __expf(-zf));
            float og = 1.f / (1.f + __expf(-zo));
            float gg = tanhf(zg);
            size_t off = ((size_t)(b * HC_ + oc) * HH + y) * WW + x;
            float cn = fg * cin[off] + ig * gg;
            out[off] = og * tanhf(cn);
            out[plane + off] = cn;
        }
    }
}

extern "C" void kernel_launch(void* const* d_in, const int* in_sizes, int n_in,
                              void* d_out, int out_size, void* d_ws, size_t ws_size,
                              hipStream_t stream) {
    // setup_inputs order:
    // 0:x 1:hidden 2:cell 3:w_xi 4:b_xi 5:w_xf 6:b_xf 7:w_xo 8:b_xo 9:w_xg 10:b_xg
    // 11:w_hi 12:b_hi 13:w_hf 14:b_hf 15:w_ho 16:b_ho 17:w_hg 18:b_hg
    PackArgs pa;
    pa.wx[0] = (const float*)d_in[3];  pa.bx[0] = (const float*)d_in[4];
    pa.wx[1] = (const float*)d_in[5];  pa.bx[1] = (const float*)d_in[6];
    pa.wx[2] = (const float*)d_in[7];  pa.bx[2] = (const float*)d_in[8];
    pa.wx[3] = (const float*)d_in[9];  pa.bx[3] = (const float*)d_in[10];
    pa.wh[0] = (const float*)d_in[11]; pa.bh[0] = (const float*)d_in[12];
    pa.wh[1] = (const float*)d_in[13]; pa.bh[1] = (const float*)d_in[14];
    pa.wh[2] = (const float*)d_in[15]; pa.bh[2] = (const float*)d_in[16];
    pa.wh[3] = (const float*)d_in[17]; pa.bh[3] = (const float*)d_in[18];

    short* a_pk = (short*)d_ws;                                  // 442368 B
    float* bias = (float*)((char*)d_ws + A_ELEMS * sizeof(short)); // +1024 B

    pack_weights<<<dim3((A_ELEMS + 255) / 256), dim3(256), 0, stream>>>(pa, a_pk, bias);
    convlstm_main<<<dim3(B_ * HH / 2), dim3(512), 0, stream>>>(
        (const float*)d_in[0], (const float*)d_in[1], (const float*)d_in[2],
        a_pk, bias, (float*)d_out);
}

// Round 2
// 291.322 us; speedup vs baseline: 1.1391x; 1.1391x over previous
//
#include <hip/hip_runtime.h>

// ConvLSTM cell on MI355X (gfx950) — round 2.
// Implicit GEMM M=256 (4 gates x 64 oc), K=864 (96ch x 9 taps), N=131072.
// bf16 MFMA 32x32x16 (2x FLOP/operand-byte vs 16x16x32), fp32 accum.
// Pre-pass packs x||h -> bf16 NHWC P[b][66][66][96] (zero borders, LDS
// chunk-swizzle baked in) so the main kernel stages via pure contiguous
// global_load_lds dwordx4 (no bounds checks, no conversion VALU).

#define B_   32
#define CIN  32
#define HC_  64
#define HH   64
#define WW   64

#define A_ELEMS (8 * 54 * 64 * 8)        // 221184 bf16 of packed A (256 x 864)
#define P_ROW   (66 * 96)                // shorts per padded NHWC row = 6336
#define P_ELEMS (B_ * 66 * P_ROW)        // 13,381,632 shorts = 26.76 MB

typedef __attribute__((ext_vector_type(8)))  short  short8;
typedef __attribute__((ext_vector_type(16))) float  floatx16;

struct PackArgs {
    const float* wx[4]; const float* wh[4];
    const float* bx[4]; const float* bh[4];
};

__device__ __forceinline__ short f2bf(float f) {
    unsigned u = __float_as_uint(f);
    u += 0x7FFFu + ((u >> 16) & 1u);     // round-to-nearest-even
    return (short)(u >> 16);
}

__device__ __forceinline__ void gl_lds16(const short* g, short* l) {
    __builtin_amdgcn_global_load_lds(
        (const __attribute__((address_space(1))) unsigned int*)g,
        (__attribute__((address_space(3))) unsigned int*)l, 16, 0, 0);
}

// ---- pack A into 32x32x16 MFMA A-fragment order ----------------------------
// flat = ((s*54 + kstep)*64 + lane)*8 + j
//   s = 32-row M-subtile: gate = s>>1, och = s&1, oc = och*32 + (lane&31)
//   kstep = tap*6 + kk ; k = (lane>>5)*8 + j ; c = kk*16 + k
__global__ __launch_bounds__(256) void pack_weights(PackArgs pa, short* a_pk, float* bias) {
    int idx = blockIdx.x * 256 + threadIdx.x;
    if (idx < A_ELEMS) {
        int j    = idx & 7;
        int lane = (idx >> 3) & 63;
        int rest = idx >> 9;             // s*54 + kstep
        int kstep = rest % 54, s = rest / 54;
        int m32 = lane & 31, hg = lane >> 5;
        int gate = s >> 1, och = s & 1;
        int oc = och * 32 + m32;
        int tap = kstep / 6, kk = kstep - 6 * tap;
        int ky = tap / 3, kx = tap - 3 * ky;
        int c = kk * 16 + hg * 8 + j;
        float v = (c < CIN)
            ? pa.wx[gate][((oc * CIN + c) * 3 + ky) * 3 + kx]
            : pa.wh[gate][((oc * HC_ + (c - CIN)) * 3 + ky) * 3 + kx];
        a_pk[idx] = f2bf(v);
    }
    if (idx < 256) {
        int gate = idx >> 6, oc = idx & 63;
        bias[idx] = pa.bx[gate][oc] + pa.bh[gate][oc];
    }
}

// ---- pack x||h -> P[b][yy][xx][c] bf16, zero borders, swizzled -------------
// Within each pixel, 16B chunk `pc` holds source chunk pc ^ (xx & 3)
// (sector-preserving XOR on low 2 bits -> write coalescing unaffected,
//  main-kernel ds_read_b128 lands balanced 8 dwords/bank).
__global__ __launch_bounds__(256) void pack_input(const float* __restrict__ x,
                                                  const float* __restrict__ h,
                                                  short* __restrict__ P) {
    const int yy = blockIdx.x, b = blockIdx.y;
    short* prow = P + ((size_t)b * 66 + yy) * P_ROW;
    int4* prow4 = (int4*)prow;                       // 792 16B chunks per row

    if (yy == 0 || yy == 65) {                       // border rows: zeros
        int4 z = {0, 0, 0, 0};
        for (int g = threadIdx.x; g < 792; g += 256) prow4[g] = z;
        return;
    }

    __shared__ short t[64 * 98];                     // [x][c], pad 96->98
    const int y = yy - 1;
    const int col = threadIdx.x & 63, cg = threadIdx.x >> 6;
    for (int c = cg; c < 96; c += 4) {
        float v = (c < CIN) ? x[((b * CIN + c) * HH + y) * WW + col]
                            : h[((b * HC_ + (c - CIN)) * HH + y) * WW + col];
        t[col * 98 + c] = f2bf(v);
    }
    __syncthreads();

    for (int g = threadIdx.x; g < 792; g += 256) {   // coalesced chunk stores
        int xx = g / 12, pc = g - xx * 12;
        int4 val = {0, 0, 0, 0};
        if (xx >= 1 && xx <= 64) {
            int sc = pc ^ (xx & 3);
            const short* sp = &t[(xx - 1) * 98 + sc * 8];
            val.x = *(const int*)(sp + 0); val.y = *(const int*)(sp + 2);
            val.z = *(const int*)(sp + 4); val.w = *(const int*)(sp + 6);
        }
        prow4[g] = val;
    }
}

// ---- main: grid 512 = (b)x(row-group of 4), 512 thr = 8 waves --------------
// wave = (nh<<1)|och : nh = output row 0..3, och = oc-half 0..1.
// Wave tile: 4 gates x 32 oc x 64 cols; acc[4][2] of 16 fp32.
__global__ __launch_bounds__(512) void convlstm_main(
    const short* __restrict__ P, const short* __restrict__ a_pk,
    const float* __restrict__ bias, const float* __restrict__ cell,
    float* __restrict__ out)
{
    __shared__ __align__(16) short in_s[6 * 66 * 96];   // 76032 B, 2 blocks/CU

    const int tid = threadIdx.x;
    const int b  = blockIdx.x >> 4;
    const int r0 = (blockIdx.x & 15) * 4;

    const int lane = tid & 63;
    const int ln31 = lane & 31, hg = lane >> 5;
    const int wv = tid >> 6;
    const int och = wv & 1, nh = wv >> 1;

    // ---- stage rows r0-1..r0+4 (= P rows r0..r0+5), one contiguous copy
    {
        const short* src = P + ((size_t)b * 66 + r0) * P_ROW;
        #pragma unroll
        for (int i = 0; i < 10; ++i) {
            int id = i * 512 + wv * 64 + lane;          // 16B-chunk index
            if (id < 4752)
                gl_lds16(src + id * 8, in_s + (i * 512 + wv * 64) * 8);
        }
    }
    __syncthreads();

    floatx16 acc[4][2];
    #pragma unroll
    for (int g = 0; g < 4; ++g)
        #pragma unroll
        for (int ns = 0; ns < 2; ++ns)
            #pragma unroll
            for (int q = 0; q < 16; ++q) acc[g][ns][q] = 0.f;

    const short8* Ap = (const short8*)a_pk;

    for (int ky = 0; ky < 3; ++ky)
    for (int kx = 0; kx < 3; ++kx) {
        const int tap = ky * 3 + kx;
        #pragma unroll
        for (int kk = 0; kk < 6; ++kk) {
            const int kstep = tap * 6 + kk;
            short8 af[4];
            #pragma unroll
            for (int g = 0; g < 4; ++g)
                af[g] = Ap[((g * 2 + och) * 54 + kstep) * 64 + lane];
            short8 bf[2];
            #pragma unroll
            for (int ns = 0; ns < 2; ++ns) {
                const int col = kx + ns * 32 + ln31;
                const int cp  = (2 * kk + hg) ^ (col & 3);
                bf[ns] = *(const short8*)&in_s[(((nh + ky) * 66 + col) * 12 + cp) * 8];
            }
            #pragma unroll
            for (int g = 0; g < 4; ++g)
                #pragma unroll
                for (int ns = 0; ns < 2; ++ns)
                    acc[g][ns] = __builtin_amdgcn_mfma_f32_32x32x16_bf16(
                        af[g], bf[ns], acc[g][ns], 0, 0, 0);
        }
    }

    // ---- fused LSTM epilogue (wave owns all 4 gates of its 32 ocs)
    const int y = r0 + nh;
    const size_t plane = (size_t)B_ * HC_ * HH * WW;
    #pragma unroll
    for (int ns = 0; ns < 2; ++ns) {
        const int x = ns * 32 + ln31;
        #pragma unroll
        for (int reg = 0; reg < 16; ++reg) {
            const int oc = och * 32 + (reg & 3) + 4 * hg + 8 * (reg >> 2);
            float zi = acc[0][ns][reg] + bias[oc];
            float zf = acc[1][ns][reg] + bias[64 + oc];
            float zo = acc[2][ns][reg] + bias[128 + oc];
            float zg = acc[3][ns][reg] + bias[192 + oc];
            float ig = 1.f / (1.f + __expf(-zi));
            float fg = 1.f / (1.f + __expf(-zf));
            float og = 1.f / (1.f + __expf(-zo));
            float e2 = __expf(2.f * zg);
            float gg = 1.f - 2.f / (e2 + 1.f);          // tanh
            size_t off = ((size_t)(b * HC_ + oc) * HH + y) * WW + x;
            float cn = fg * cell[off] + ig * gg;
            float ec = __expf(2.f * cn);
            out[off] = og * (1.f - 2.f / (ec + 1.f));   // h_new
            out[plane + off] = cn;                       // c_new
        }
    }
}

extern "C" void kernel_launch(void* const* d_in, const int* in_sizes, int n_in,
                              void* d_out, int out_size, void* d_ws, size_t ws_size,
                              hipStream_t stream) {
    PackArgs pa;
    pa.wx[0] = (const float*)d_in[3];  pa.bx[0] = (const float*)d_in[4];
    pa.wx[1] = (const float*)d_in[5];  pa.bx[1] = (const float*)d_in[6];
    pa.wx[2] = (const float*)d_in[7];  pa.bx[2] = (const float*)d_in[8];
    pa.wx[3] = (const float*)d_in[9];  pa.bx[3] = (const float*)d_in[10];
    pa.wh[0] = (const float*)d_in[11]; pa.bh[0] = (const float*)d_in[12];
    pa.wh[1] = (const float*)d_in[13]; pa.bh[1] = (const float*)d_in[14];
    pa.wh[2] = (const float*)d_in[15]; pa.bh[2] = (const float*)d_in[16];
    pa.wh[3] = (const float*)d_in[17]; pa.bh[3] = (const float*)d_in[18];

    short* a_pk = (short*)d_ws;                                   // 442368 B
    float* bias = (float*)((char*)d_ws + A_ELEMS * sizeof(short)); // 1024 B
    short* P    = (short*)((char*)d_ws + 443392);                 // 26.76 MB

    pack_weights<<<dim3(A_ELEMS / 256), dim3(256), 0, stream>>>(pa, a_pk, bias);
    pack_input <<<dim3(66, B_), dim3(256), 0, stream>>>(
        (const float*)d_in[0], (const float*)d_in[1], P);
    convlstm_main<<<dim3(B_ * 16), dim3(512), 0, stream>>>(
        P, a_pk, bias, (const float*)d_in[2], (float*)d_out);
}

// Round 3
// 227.854 us; speedup vs baseline: 1.4564x; 1.2785x over previous
//
#include <hip/hip_runtime.h>

// ConvLSTM cell on MI355X (gfx950) — round 3.
// Implicit GEMM M=256 (4 gates x 64 oc), K=864 (96ch x 9 taps), N=131072.
// bf16 MFMA 32x32x16. Wave tile M=64 (4 gates x 16 oc -> lane-local LSTM
// epilogue) x N=64, acc = 64 AGPRs -> 4 waves/SIMD.
// A: per-tap 48KB LDS slab via global_load_lds; frags via ds_read_b128.
// B: direct global dwordx4 from P'[b][yy][pc12][xx66][8ch] (coalesced, L1/L2).

#define B_   32
#define CIN  32
#define HC_  64
#define HH   64
#define WW   64

#define A_ELEMS (9 * 8 * 6 * 64 * 8)     // 221184 bf16 = 256 x 864 packed A
#define P_ROW   (12 * 66 * 8)            // shorts per P' row = 6336
#define SLAB    24576                    // shorts per tap slab (48 KB)

typedef __attribute__((ext_vector_type(8)))  short  short8;
typedef __attribute__((ext_vector_type(16))) float  floatx16;

struct PackArgs {
    const float* wx[4]; const float* wh[4];
    const float* bx[4]; const float* bh[4];
};

__device__ __forceinline__ short f2bf(float f) {
    unsigned u = __float_as_uint(f);
    u += 0x7FFFu + ((u >> 16) & 1u);     // round-to-nearest-even
    return (short)(u >> 16);
}

__device__ __forceinline__ void gl_lds16(const short* g, short* l) {
    __builtin_amdgcn_global_load_lds(
        (const __attribute__((address_space(1))) unsigned int*)g,
        (__attribute__((address_space(3))) unsigned int*)l, 16, 0, 0);
}

// ---- pack A: [tap 9][s 8][kk 6][lane 64][j 8] ------------------------------
// s = og*2+fi ; m32 = lane&31 ; gate = 2*fi + (m32>>4) ; oc = og*16 + (m32&15)
// c = kk*16 + (lane>>5)*8 + j  (A-operand: m = lane&31, k = (lane>>5)*8+j)
__global__ __launch_bounds__(256) void pack_weights(PackArgs pa, short* a_pk, float* bias) {
    int idx = blockIdx.x * 256 + threadIdx.x;
    if (idx < A_ELEMS) {
        int j    = idx & 7;
        int lane = (idx >> 3) & 63;
        int rest = idx >> 9;             // (tap*8+s)*6 + kk
        int kk   = rest % 6;
        int rest2 = rest / 6;
        int s    = rest2 % 8;
        int tap  = rest2 / 8;
        int og = s >> 1, fi = s & 1;
        int m32 = lane & 31;
        int gate = 2 * fi + (m32 >> 4);
        int oc   = og * 16 + (m32 & 15);
        int c    = kk * 16 + (lane >> 5) * 8 + j;
        int ky = tap / 3, kx = tap - 3 * ky;
        float v = (c < CIN)
            ? pa.wx[gate][((oc * CIN + c) * 3 + ky) * 3 + kx]
            : pa.wh[gate][((oc * HC_ + (c - CIN)) * 3 + ky) * 3 + kx];
        a_pk[idx] = f2bf(v);
    }
    if (idx < 256) {
        int gate = idx >> 6, oc = idx & 63;
        bias[idx] = pa.bx[gate][oc] + pa.bh[gate][oc];
    }
}

// ---- pack x||h -> P'[b][yy][pc 12][xx 66][8ch] bf16, zero borders ----------
__global__ __launch_bounds__(256) void pack_input(const float* __restrict__ x,
                                                  const float* __restrict__ h,
                                                  short* __restrict__ P) {
    const int yy = blockIdx.x, b = blockIdx.y;
    int4* prow4 = (int4*)(P + ((size_t)b * 66 + yy) * P_ROW);  // 792 chunks

    if (yy == 0 || yy == 65) {
        int4 z = {0, 0, 0, 0};
        for (int g = threadIdx.x; g < 792; g += 256) prow4[g] = z;
        return;
    }

    __shared__ short t[64 * 98];                     // [x][c], pad 96->98
    const int y = yy - 1;
    const int col = threadIdx.x & 63, cg = threadIdx.x >> 6;
    for (int c = cg; c < 96; c += 4) {
        float v = (c < CIN) ? x[((b * CIN + c) * HH + y) * WW + col]
                            : h[((b * HC_ + (c - CIN)) * HH + y) * WW + col];
        t[col * 98 + c] = f2bf(v);
    }
    __syncthreads();

    for (int g = threadIdx.x; g < 792; g += 256) {   // pc = g/66, xx = g%66
        int pc = g / 66, xx = g - 66 * pc;
        int4 val = {0, 0, 0, 0};
        if (xx >= 1 && xx <= 64) {
            const short* sp = &t[(xx - 1) * 98 + pc * 8];
            val.x = *(const int*)(sp + 0); val.y = *(const int*)(sp + 2);
            val.z = *(const int*)(sp + 4); val.w = *(const int*)(sp + 6);
        }
        prow4[g] = val;
    }
}

// ---- main: grid 1024 = (b 32)x(rowgroup 32 of 2 rows), 512 thr = 8 waves ---
// wave = og(0..3) x nh(0..1): M-tile = 4 gates x 16 oc (og), N = row y0+nh,
// 64 cols. acc[fi][ns] (fi = gate-pair, ns = col-half), 64 AGPR total.
__global__ __launch_bounds__(512, 4) void convlstm_main(
    const short* __restrict__ P, const short* __restrict__ a_pk,
    const float* __restrict__ bias, const float* __restrict__ cell,
    float* __restrict__ out)
{
    __shared__ __align__(16) short As[SLAB];         // 48 KB -> 2 blocks/CU

    const int tid = threadIdx.x;
    const int b  = blockIdx.x >> 5;
    const int y0 = (blockIdx.x & 31) * 2;

    const int wv = tid >> 6, lane = tid & 63;
    const int ln31 = lane & 31, hg = lane >> 5;
    const int og = wv & 3, nh = wv >> 2;
    const int y = y0 + nh;

    floatx16 acc[2][2];
    #pragma unroll
    for (int fi = 0; fi < 2; ++fi)
        #pragma unroll
        for (int ns = 0; ns < 2; ++ns)
            #pragma unroll
            for (int q = 0; q < 16; ++q) acc[fi][ns][q] = 0.f;

    // wave-constant pieces
    const int a_base = og * 12 * 64 * 8 + lane * 8;          // + (fi*6+kk)*512
    const int lnoff  = (hg * 66 + ln31) * 8;                 // B per-lane offset

    for (int ky = 0; ky < 3; ++ky)
    for (int kx = 0; kx < 3; ++kx) {
        const int tap = ky * 3 + kx;
        // ---- stage A slab for this tap (3072 chunks / 512 thr = 6 each)
        {
            const short* slab = a_pk + tap * SLAB;
            #pragma unroll
            for (int i = 0; i < 6; ++i) {
                int id = i * 512 + tid;
                gl_lds16(slab + id * 8, As + (i * 512 + wv * 64) * 8);
            }
        }
        __syncthreads();

        const short* Brow = P + ((size_t)(b * 66) + y + ky) * P_ROW + kx * 8 + lnoff;

        #pragma unroll
        for (int kk = 0; kk < 6; ++kk) {
            short8 a0 = *(const short8*)&As[a_base + (0 * 6 + kk) * 512];
            short8 a1 = *(const short8*)&As[a_base + (1 * 6 + kk) * 512];
            short8 b0 = *(const short8*)&Brow[(2 * kk * 66 + 0 ) * 8];
            short8 b1 = *(const short8*)&Brow[(2 * kk * 66 + 32) * 8];
            acc[0][0] = __builtin_amdgcn_mfma_f32_32x32x16_bf16(a0, b0, acc[0][0], 0, 0, 0);
            acc[0][1] = __builtin_amdgcn_mfma_f32_32x32x16_bf16(a0, b1, acc[0][1], 0, 0, 0);
            acc[1][0] = __builtin_amdgcn_mfma_f32_32x32x16_bf16(a1, b0, acc[1][0], 0, 0, 0);
            acc[1][1] = __builtin_amdgcn_mfma_f32_32x32x16_bf16(a1, b1, acc[1][1], 0, 0, 0);
        }
        __syncthreads();
    }

    // ---- lane-local LSTM epilogue --------------------------------------
    // C/D 32x32 map: col = ln31, row r32 = (r&3) + 4*hg + 8*(r>>2).
    // acc[fi][.] rows: r32<16 -> gate 2fi, oc16=r32 ; r32>=16 -> gate 2fi+1.
    const size_t plane = (size_t)B_ * HC_ * HH * WW;
    #pragma unroll
    for (int q = 0; q < 4; ++q)
    #pragma unroll
    for (int b8 = 0; b8 < 2; ++b8) {
        const int oc16 = q + 4 * hg + 8 * b8;
        const int oc = og * 16 + oc16;
        const float Bi = bias[oc],       Bf = bias[64 + oc];
        const float Bo = bias[128 + oc], Bg = bias[192 + oc];
        const int r_lo = q + 4 * b8, r_hi = q + 4 * (2 + b8);
        #pragma unroll
        for (int ns = 0; ns < 2; ++ns) {
            float zi = acc[0][ns][r_lo] + Bi;
            float zf = acc[0][ns][r_hi] + Bf;
            float zo = acc[1][ns][r_lo] + Bo;
            float zg = acc[1][ns][r_hi] + Bg;
            float ig = 1.f / (1.f + __expf(-zi));
            float fg = 1.f / (1.f + __expf(-zf));
            float sg = 1.f / (1.f + __expf(-zo));
            float e2 = __expf(2.f * zg);
            float gg = 1.f - 2.f / (e2 + 1.f);               // tanh(zg)
            const int x = ns * 32 + ln31;
            size_t off = ((size_t)(b * HC_ + oc) * HH + y) * WW + x;
            float cn = fg * cell[off] + ig * gg;
            float ec = __expf(2.f * cn);
            out[off] = sg * (1.f - 2.f / (ec + 1.f));        // h_new
            out[plane + off] = cn;                           // c_new
        }
    }
}

extern "C" void kernel_launch(void* const* d_in, const int* in_sizes, int n_in,
                              void* d_out, int out_size, void* d_ws, size_t ws_size,
                              hipStream_t stream) {
    PackArgs pa;
    pa.wx[0] = (const float*)d_in[3];  pa.bx[0] = (const float*)d_in[4];
    pa.wx[1] = (const float*)d_in[5];  pa.bx[1] = (const float*)d_in[6];
    pa.wx[2] = (const float*)d_in[7];  pa.bx[2] = (const float*)d_in[8];
    pa.wx[3] = (const float*)d_in[9];  pa.bx[3] = (const float*)d_in[10];
    pa.wh[0] = (const float*)d_in[11]; pa.bh[0] = (const float*)d_in[12];
    pa.wh[1] = (const float*)d_in[13]; pa.bh[1] = (const float*)d_in[14];
    pa.wh[2] = (const float*)d_in[15]; pa.bh[2] = (const float*)d_in[16];
    pa.wh[3] = (const float*)d_in[17]; pa.bh[3] = (const float*)d_in[18];

    short* a_pk = (short*)d_ws;                                    // 442368 B
    float* bias = (float*)((char*)d_ws + A_ELEMS * sizeof(short)); // 1024 B
    short* P    = (short*)((char*)d_ws + 443392);                  // 26.76 MB

    pack_weights<<<dim3(A_ELEMS / 256), dim3(256), 0, stream>>>(pa, a_pk, bias);
    pack_input <<<dim3(66, B_), dim3(256), 0, stream>>>(
        (const float*)d_in[0], (const float*)d_in[1], P);
    convlstm_main<<<dim3(B_ * 32), dim3(512), 0, stream>>>(
        P, a_pk, bias, (const float*)d_in[2], (float*)d_out);
}